// Round 1
// 224.314 us; speedup vs baseline: 1.0148x; 1.0148x over previous
//
#include <hip/hip_runtime.h>

// Problem constants (from reference):
//   x: [B=32, C=1, F=257, T=4096] float32 log-magnitude spectrogram
//   SHIFT_BINS = 20.0 / (16000/512) = 0.64  -> f_low = f, f_high = f+1
//   out[b,f,t] = log10((1-a)*10^x[b,f,t] + a*10^x[b,f+1,t] + 1e-8), f < 256
//   out[b,256,t] = log10(1e-8)   (valid mask false at the top bin)
#define B_DIM 32
#define F_DIM 257
#define T_DIM 4096
#define EPS_F 1e-8f

// log2(10) and log10(2) in fp32-exact-enough form
#define LOG2_10  3.32192809488736234787f
#define LOG10_2  0.30102999566398119521f

// ext_vector type so __builtin_nontemporal_store accepts it directly
typedef float f32x4 __attribute__((ext_vector_type(4)));

__device__ __forceinline__ float pow10_fast(float v) {
    // 10^v = 2^(v * log2(10)); v_exp_f32 is ~1 ulp — far under the absmax threshold
    return __builtin_amdgcn_exp2f(v * LOG2_10);
}

__device__ __forceinline__ float log10_fast(float v) {
    return __builtin_amdgcn_logf(v) * LOG10_2;  // v_log_f32 is log2
}

__global__ __launch_bounds__(256) void freq_shift_kernel(
        const float* __restrict__ x, float* __restrict__ out) {
    const int bf = blockIdx.x;            // flattened (b*F + f); rows are contiguous
    const int f  = bf % F_DIM;
    const long long base = (long long)bf * T_DIM;
    const int tid = threadIdx.x;

    f32x4* __restrict__ orow = (f32x4*)(out + base);

    if (f == F_DIM - 1) {
        // invalid top bin: log10(0 + 1e-8); block-uniform branch, no divergence
        const float cv = log10_fast(EPS_F);
        f32x4 v;
        v.x = cv; v.y = cv; v.z = cv; v.w = cv;
#pragma unroll
        for (int i = 0; i < T_DIM / 4 / 256; ++i)
            __builtin_nontemporal_store(v, orow + i * 256 + tid);
        return;
    }

    const f32x4* __restrict__ row0 = (const f32x4*)(x + base);
    const f32x4* __restrict__ row1 = (const f32x4*)(x + base + T_DIM);

    // Reproduce reference fp32 alpha: target = fl(f + 0.64f); alpha = target - f
    // (exact subtraction by Sterbenz; matches jnp float32 weak-typed arithmetic)
    const float ff     = (float)f;
    const float target = ff + 0.64f;
    const float alpha  = target - ff;
    const float beta   = 1.0f - alpha;

    // Stage ALL loads before any compute: 8 global_load_dwordx4 in flight per
    // thread (128 B) instead of the compiler's load-pair/wait/compute schedule
    // (VGPR_Count=24 showed only ~2 loads outstanding -> latency-bound 3.3 TB/s).
    f32x4 va[4], vb[4];
#pragma unroll
    for (int i = 0; i < 4; ++i) va[i] = row0[i * 256 + tid];
#pragma unroll
    for (int i = 0; i < 4; ++i) vb[i] = row1[i * 256 + tid];

#pragma unroll
    for (int i = 0; i < 4; ++i) {
        f32x4 r;
        r.x = log10_fast(beta * pow10_fast(va[i].x) + alpha * pow10_fast(vb[i].x) + EPS_F);
        r.y = log10_fast(beta * pow10_fast(va[i].y) + alpha * pow10_fast(vb[i].y) + EPS_F);
        r.z = log10_fast(beta * pow10_fast(va[i].z) + alpha * pow10_fast(vb[i].z) + EPS_F);
        r.w = log10_fast(beta * pow10_fast(va[i].w) + alpha * pow10_fast(vb[i].w) + EPS_F);
        // out is write-once, never re-read: nontemporal store keeps L2/L3 lines
        // free for the row f+1 re-read dedup.
        __builtin_nontemporal_store(r, orow + i * 256 + tid);
    }
}

extern "C" void kernel_launch(void* const* d_in, const int* in_sizes, int n_in,
                              void* d_out, int out_size, void* d_ws, size_t ws_size,
                              hipStream_t stream) {
    const float* x = (const float*)d_in[0];
    float* out = (float*)d_out;
    // grid: one block per (b,f) row; 32*257 = 8224 blocks, 256 threads,
    // 4 float4 iterations per thread covering T=4096
    dim3 grid(B_DIM * F_DIM);
    dim3 block(256);
    freq_shift_kernel<<<grid, block, 0, stream>>>(x, out);
}